// Round 25
// baseline (91.486 us; speedup 1.0000x reference)
//
#include <hip/hip_runtime.h>
#include <math.h>

typedef __attribute__((ext_vector_type(8))) short bf16x8;
typedef __attribute__((ext_vector_type(4))) float f32x4;
typedef unsigned short u16;

__device__ __forceinline__ unsigned short f2bf(float f) {
    unsigned u = __builtin_bit_cast(unsigned, f);
    u += 0x7fffu + ((u >> 16) & 1u);          // round-to-nearest-even
    return (unsigned short)(u >> 16);
}
__device__ __forceinline__ float bf2f(unsigned short v) {
    return __builtin_bit_cast(float, (unsigned)v << 16);
}

// ---------------------------------------------------------------------------
// Prep: 384 blocks, one wave each (proven build path).
// P1: [256 cols][128 k] block-16 output cols (stage-1 B; k = raw x feature).
// P2: [256 cols][256 k] with k-rows INTERLEAVED (k=2r -> Re of input feature
//     r, k=2r+1 -> Im) — R20-proven variant, matches interleaved z layout.
// P3: [256 cols][256 k] block-16 both axes (consumed only by combine).
// ---------------------------------------------------------------------------
__global__ __launch_bounds__(128) void prep_all_kernel(
    const float* __restrict__ mzi1, const float* __restrict__ mzi2,
    const float* __restrict__ mzi3, const float* __restrict__ inph,
    const float* __restrict__ outph1, const float* __restrict__ outph2,
    const float* __restrict__ outph3,
    u16* __restrict__ P1, u16* __restrict__ P2, u16* __restrict__ P3)
{
    const int b = blockIdx.x, t = threadIdx.x;
    if (t >= 64) return;               // one wave per block

    const int s = b >> 7, r = b & 127;
    const float* mzi = (s == 0) ? mzi1 : ((s == 1) ? mzi2 : mzi3);

    float2 a = make_float2(0.f, 0.f), b2 = make_float2(0.f, 0.f);
    if (s == 0) {
        float sp, cp; __sincosf(inph[r], &sp, &cp);
        if (2 * t == r)     a  = make_float2(cp, sp);
        if (2 * t + 1 == r) b2 = make_float2(cp, sp);
    } else {
        if (2 * t == r)     a.x  = 1.f;
        if (2 * t + 1 == r) b2.x = 1.f;
    }

    auto ldmz = [&](int L) -> float2 {
        const int start = L & 1;
        const int m = 64 - start;
        if (t < m) {
            const int off = (L >> 1) * 254 + start * 128 + 2 * t;
            return *(const float2*)(mzi + off);
        }
        return make_float2(0.f, 0.f);
    };
    float2 mz[4];
    #pragma unroll
    for (int i = 0; i < 4; ++i) mz[i] = ldmz(i);

    #pragma unroll 4
    for (int L = 0; L < 128; ++L) {
        const float2 v = mz[L & 3];
        if (L < 124) mz[L & 3] = ldmz(L + 4);
        float st, ct, sp, cp;
        __sincosf(v.x, &st, &ct);
        __sincosf(v.y, &sp, &cp);
        if ((L & 1) == 0) {
            float pr = ct * (a.x * cp - a.y * sp) + st * b2.x;
            float pi = ct * (a.x * sp + a.y * cp) + st * b2.y;
            float qr = st * a.x - ct * (b2.x * cp + b2.y * sp);
            float qi = st * a.y - ct * (b2.y * cp - b2.x * sp);
            a = make_float2(pr, pi); b2 = make_float2(qr, qi);
        } else {
            float2 an;
            an.x = __shfl_down(a.x, 1); an.y = __shfl_down(a.y, 1);
            float pr = ct * (b2.x * cp - b2.y * sp) + st * an.x;
            float pi = ct * (b2.x * sp + b2.y * cp) + st * an.y;
            float qr = st * b2.x - ct * (an.x * cp + an.y * sp);
            float qi = st * b2.y - ct * (an.y * cp - an.x * sp);
            if (t < 63) b2 = make_float2(pr, pi);
            float2 qs;
            qs.x = __shfl_up(qr, 1); qs.y = __shfl_up(qi, 1);
            if (t >= 1) a = qs;
        }
    }

    const float* outph = (s == 0) ? outph1 : ((s == 1) ? outph2 : outph3);
    #pragma unroll
    for (int h = 0; h < 2; ++h) {
        const int j = 2 * t + h;
        float2 w = h ? b2 : a;
        float sp, cp; __sincosf(outph[j], &sp, &cp);
        const float wr = w.x * cp - w.y * sp;
        const float wi = w.x * sp + w.y * cp;
        const int cre = ((j >> 4) * 32) + (j & 15);
        if (s == 0) {
            P1[cre * 128 + r]        = f2bf(wr);
            P1[(cre + 16) * 128 + r] = f2bf(wi);
        } else if (s == 1) {
            // interleaved k-rows (R20-proven)
            P2[cre * 256 + 2 * r]            = f2bf(wr);
            P2[cre * 256 + 2 * r + 1]        = f2bf(-wi);
            P2[(cre + 16) * 256 + 2 * r]     = f2bf(wi);
            P2[(cre + 16) * 256 + 2 * r + 1] = f2bf(wr);
        } else {
            const int rre = ((r >> 4) * 32) + (r & 15);
            P3[cre * 256 + rre]             = f2bf(wr);
            P3[cre * 256 + rre + 16]        = f2bf(-wi);
            P3[(cre + 16) * 256 + rre]      = f2bf(wi);
            P3[(cre + 16) * 256 + rre + 16] = f2bf(wr);
        }
    }
}

// ---------------------------------------------------------------------------
// Combine (R22-proven math, ~2-3us): P34[n][k'] = sum_c P3[c*256+k]*Wval(n,c)
// with the OUTPUT index remapped from block-16 k to INTERLEAVED k':
// k = g*32+i -> feature r = g*16+(i&15), k' = 2r + (i>>4).
// (Derivation checked against prep identities: P34[n][2r] = sum_c(Re*W[n][c]
//  + Im*W[n][c+128]); P34[n][2r+1] = sum_c(-Im*W[n][c] + Re*W[n][c+128]).)
// ---------------------------------------------------------------------------
__global__ __launch_bounds__(256) void combine_kernel(
    const u16* __restrict__ P3, const float* __restrict__ W,
    u16* __restrict__ P34)
{
    __shared__ float partial[8][256];
    const int n  = blockIdx.x;     // 0..127 output col
    const int t  = threadIdx.x;
    const int cs = t >> 5;         // 0..7 c-slice
    const int kb = (t & 31) * 8;   // k base (block-16 index)

    float acc[8];
    #pragma unroll
    for (int e = 0; e < 8; ++e) acc[e] = 0.f;

    #pragma unroll 4
    for (int cc = 0; cc < 32; ++cc) {
        const int c = cs * 32 + cc;
        const int j = (cc < 16) ? (cs * 16 + cc) : (128 + cs * 16 + (cc - 16));
        const float w = W[n * 256 + j];
        bf16x8 p = *(const bf16x8*)&P3[c * 256 + kb];
        #pragma unroll
        for (int e = 0; e < 8; ++e)
            acc[e] = fmaf(bf2f((unsigned short)p[e]), w, acc[e]);
    }

    #pragma unroll
    for (int e = 0; e < 8; ++e) partial[cs][kb + e] = acc[e];
    __syncthreads();

    if (cs == 0) {
        #pragma unroll
        for (int e = 0; e < 8; ++e) {
            float s = 0.f;
            #pragma unroll
            for (int q = 0; q < 8; ++q) s += partial[q][kb + e];
            const int k = kb + e;
            const int g = k >> 5, i = k & 31;
            const int rf = g * 16 + (i & 15);
            P34[n * 256 + 2 * rf + (i >> 4)] = f2bf(s);
        }
    }
}

// ---------------------------------------------------------------------------
// SPLIT PIPELINE (R25): three independent streaming GEMM kernels; z1/z2 live
// IN d_out (bf16 interleaved [row][2f]=re,[2f+1]=im; 65536x256x2B = exactly
// out_size bytes). Each block reads ONLY its own 64-row range into LDS,
// barriers, then overwrites the same range -> in-place chaining is safe.
// No inter-stage barriers: blocks decouple, staging/GEMM/stores of different
// blocks pipeline (the fused kernel's 5-phase coupling was the 57us wall;
// pipe sums were only ~40us). Proven components: R22 staging/GEMM/nofu,
// R20 interleaved layout, 1M x 8N wave split, unroll-2 k-loops, (512,4).
// ---------------------------------------------------------------------------

// K1: z1 = nofu1(x @ P1) -> d_out (interleaved bf16)
__global__ __launch_bounds__(512, 4) void stage1_kernel(
    const float* __restrict__ x, const u16* __restrict__ P1,
    const float* __restrict__ al1, const float* __restrict__ be1,
    u16* z)
{
    __shared__ __align__(16) char zA[32768];   // [64 rows][128 cols fp32->bf16... stored as 256 k bf16? no: 64x128 bf16 = 16KB] 
    // NOTE: x has K=128 -> tile is [64 rows][128 k] bf16 = 16KB; keep 32KB decl for uniformity is wasteful -> use 16KB.
    // (shared decl actually 16KB:)
    // -- replaced below --
    (void)zA;
    __shared__ __align__(16) char xT[16384];   // [64 rows][128 k] bf16, swizzled

    const int tid  = threadIdx.x;
    const int lane = tid & 63;
    const int wv   = tid >> 6;        // 0..7 (N-split)
    const int l16  = lane & 15;
    const int kg   = lane >> 4;
    const int nb   = wv * 32;
    const size_t rowBase = (size_t)blockIdx.x * 64;

    const int jf = wv * 16 + l16;
    const float av1 = 0.5f * fminf(fmaxf(al1[jf], 0.f), 10.f);
    const float bv1 = fminf(fmaxf(be1[jf], 0.f), 10.f);

    // stage x (64 rows x 128 fp32) -> xT bf16 swizzled ([row][128 k], 256B rows)
    {
        const float4* xg = (const float4*)(x + rowBase * 128);
        #pragma unroll
        for (int i = 0; i < 4; ++i) {
            const int idx = tid + i * 512;        // 0..2047
            const int row = idx >> 5;             // 32 float4 per row
            const int c4  = idx & 31;
            float4 f = xg[idx];
            uint2 v;
            v.x = (unsigned)f2bf(f.x) | ((unsigned)f2bf(f.y) << 16);
            v.y = (unsigned)f2bf(f.z) | ((unsigned)f2bf(f.w) << 16);
            const unsigned byte = ((unsigned)(row * 256 + c4 * 8)) ^ ((unsigned)(row & 15) << 4);
            *(uint2*)(xT + byte) = v;
        }
    }
    __syncthreads();

    f32x4 acc[4][2];
    #pragma unroll
    for (int mt = 0; mt < 4; ++mt)
        #pragma unroll
        for (int nt = 0; nt < 2; ++nt) acc[mt][nt] = (f32x4){0.f, 0.f, 0.f, 0.f};

    #pragma unroll 2
    for (int ksl = 0; ksl < 4; ++ksl) {
        const int k0 = ksl * 32 + kg * 8;
        bf16x8 A[4];
        #pragma unroll
        for (int mt = 0; mt < 4; ++mt) {
            const int row = mt * 16 + l16;
            const unsigned byte = ((unsigned)(row * 256 + k0 * 2)) ^ ((unsigned)(row & 15) << 4);
            A[mt] = *(const bf16x8*)(xT + byte);
        }
        #pragma unroll
        for (int nt = 0; nt < 2; ++nt) {
            bf16x8 Bf = *(const bf16x8*)&P1[(nb + nt * 16 + l16) * 128 + k0];
            #pragma unroll
            for (int mt = 0; mt < 4; ++mt)
                acc[mt][nt] = __builtin_amdgcn_mfma_f32_16x16x32_bf16(A[mt], Bf, acc[mt][nt], 0, 0, 0);
        }
    }

    // nofu1 + write z1 interleaved (u32 -> 64B bursts per 16-lane group)
    #pragma unroll
    for (int mt = 0; mt < 4; ++mt)
        #pragma unroll
        for (int r = 0; r < 4; ++r) {
            float re = acc[mt][0][r], im = acc[mt][1][r];
            float I = fmaf(re, re, fmaf(im, im, 1e-8f));
            float fct = __expf(__fdividef(-av1, fmaf(bv1, I, 1.f)));
            re *= fct; im *= fct;
            unsigned pk = (unsigned)f2bf(re) | ((unsigned)f2bf(im) << 16);
            const size_t row = rowBase + mt * 16 + kg * 4 + r;
            *(unsigned*)(z + row * 256 + 2 * jf) = pk;
        }
}

// K2: z2 = nofu2(z1 @ P2) -> in place (per-block 64-row range)
__global__ __launch_bounds__(512, 4) void stage2_kernel(
    const u16* zin, const u16* __restrict__ P2,
    const float* __restrict__ al2, const float* __restrict__ be2,
    u16* zout)
{
    __shared__ __align__(16) char zA[32768];   // [64 rows][256 k] bf16, swizzled

    const int tid  = threadIdx.x;
    const int lane = tid & 63;
    const int wv   = tid >> 6;
    const int l16  = lane & 15;
    const int kg   = lane >> 4;
    const int nb   = wv * 32;
    const size_t rowBase = (size_t)blockIdx.x * 64;

    const int jf = wv * 16 + l16;
    const float av2 = 0.5f * fminf(fmaxf(al2[jf], 0.f), 10.f);
    const float bv2 = fminf(fmaxf(be2[jf], 0.f), 10.f);

    // stage z1 (64 rows x 512B) -> zA swizzled, coalesced uint4
    {
        const uint4* zg = (const uint4*)(zin + rowBase * 256);
        #pragma unroll
        for (int i = 0; i < 4; ++i) {
            const int idx = tid + i * 512;        // 0..2047
            const int row = idx >> 5;             // 32 x 16B per row
            const int c16 = idx & 31;
            uint4 v = zg[idx];
            const unsigned byte = ((unsigned)(row * 512 + c16 * 16)) ^ ((unsigned)(row & 31) << 4);
            *(uint4*)(zA + byte) = v;
        }
    }
    __syncthreads();

    f32x4 acc[4][2];
    #pragma unroll
    for (int mt = 0; mt < 4; ++mt)
        #pragma unroll
        for (int nt = 0; nt < 2; ++nt) acc[mt][nt] = (f32x4){0.f, 0.f, 0.f, 0.f};

    #pragma unroll 2
    for (int ks = 0; ks < 8; ++ks) {
        const int k0 = ks * 32 + kg * 8;
        bf16x8 A[4];
        #pragma unroll
        for (int mt = 0; mt < 4; ++mt) {
            const int row = mt * 16 + l16;
            const unsigned byte = ((unsigned)(row * 512 + k0 * 2)) ^ ((unsigned)(row & 31) << 4);
            A[mt] = *(const bf16x8*)(zA + byte);
        }
        #pragma unroll
        for (int nt = 0; nt < 2; ++nt) {
            bf16x8 Bf = *(const bf16x8*)&P2[(nb + nt * 16 + l16) * 256 + k0];
            #pragma unroll
            for (int mt = 0; mt < 4; ++mt)
                acc[mt][nt] = __builtin_amdgcn_mfma_f32_16x16x32_bf16(A[mt], Bf, acc[mt][nt], 0, 0, 0);
        }
    }

    // nofu2 + write z2 interleaved (in place: own rows only, post-barrier)
    #pragma unroll
    for (int mt = 0; mt < 4; ++mt)
        #pragma unroll
        for (int r = 0; r < 4; ++r) {
            float re = acc[mt][0][r], im = acc[mt][1][r];
            float I = fmaf(re, re, fmaf(im, im, 1e-8f));
            float fct = __expf(__fdividef(-av2, fmaf(bv2, I, 1.f)));
            re *= fct; im *= fct;
            unsigned pk = (unsigned)f2bf(re) | ((unsigned)f2bf(im) << 16);
            const size_t row = rowBase + mt * 16 + kg * 4 + r;
            *(unsigned*)(zout + row * 256 + 2 * jf) = pk;
        }
}

// K3: out = z2 @ P34 + bias -> d_out fp32 (in place over the z2 bytes)
__global__ __launch_bounds__(512, 4) void final_kernel(
    const u16* zin, const u16* __restrict__ P34,
    const float* __restrict__ bias, float* out)
{
    __shared__ __align__(16) char zA[32768];

    const int tid  = threadIdx.x;
    const int lane = tid & 63;
    const int wv   = tid >> 6;
    const int l16  = lane & 15;
    const int kg   = lane >> 4;
    const size_t rowBase = (size_t)blockIdx.x * 64;

    // stage z2 -> zA swizzled
    {
        const uint4* zg = (const uint4*)(zin + rowBase * 256);
        #pragma unroll
        for (int i = 0; i < 4; ++i) {
            const int idx = tid + i * 512;
            const int row = idx >> 5;
            const int c16 = idx & 31;
            uint4 v = zg[idx];
            const unsigned byte = ((unsigned)(row * 512 + c16 * 16)) ^ ((unsigned)(row & 31) << 4);
            *(uint4*)(zA + byte) = v;
        }
    }
    __syncthreads();

    f32x4 facc[4];
    #pragma unroll
    for (int mt = 0; mt < 4; ++mt) facc[mt] = (f32x4){0.f, 0.f, 0.f, 0.f};

    const int nb2 = wv * 16;
    #pragma unroll 2
    for (int ks = 0; ks < 8; ++ks) {
        const int k0 = ks * 32 + kg * 8;
        bf16x8 A[4];
        #pragma unroll
        for (int mt = 0; mt < 4; ++mt) {
            const int row = mt * 16 + l16;
            const unsigned byte = ((unsigned)(row * 512 + k0 * 2)) ^ ((unsigned)(row & 31) << 4);
            A[mt] = *(const bf16x8*)(zA + byte);
        }
        bf16x8 Bf = *(const bf16x8*)&P34[(nb2 + l16) * 256 + k0];
        #pragma unroll
        for (int mt = 0; mt < 4; ++mt)
            facc[mt] = __builtin_amdgcn_mfma_f32_16x16x32_bf16(A[mt], Bf, facc[mt], 0, 0, 0);
    }

    const float bcol = bias[nb2 + l16];
    #pragma unroll
    for (int mt = 0; mt < 4; ++mt)
        #pragma unroll
        for (int r = 0; r < 4; ++r) {
            const size_t row = rowBase + mt * 16 + kg * 4 + r;
            out[row * 128 + nb2 + l16] = facc[mt][r] + bcol;
        }
}

extern "C" void kernel_launch(void* const* d_in, const int* in_sizes, int n_in,
                              void* d_out, int out_size, void* d_ws, size_t ws_size,
                              hipStream_t stream)
{
    const float* x      = (const float*)d_in[0];
    const float* inph   = (const float*)d_in[1];
    const float* mzi1   = (const float*)d_in[2];
    const float* outph1 = (const float*)d_in[3];
    const float* alpha1 = (const float*)d_in[4];
    const float* beta1  = (const float*)d_in[5];
    const float* mzi2   = (const float*)d_in[6];
    const float* outph2 = (const float*)d_in[7];
    const float* alpha2 = (const float*)d_in[8];
    const float* beta2  = (const float*)d_in[9];
    const float* mzi3   = (const float*)d_in[10];
    const float* outph3 = (const float*)d_in[11];
    const float* W      = (const float*)d_in[12];
    const float* bias   = (const float*)d_in[13];

    const int B = in_sizes[0] / 128;

    // ws: P1 64KB | P2 128KB | P3 128KB | P34 64KB = 384KB
    u16* P1  = (u16*)d_ws;
    u16* P2  = P1 + 32768;
    u16* P3  = P2 + 65536;
    u16* P34 = P3 + 65536;

    // z1/z2 live in d_out (bf16 interleaved; 65536*256*2B == out bytes)
    u16* zbuf = (u16*)d_out;

    prep_all_kernel<<<384, 128, 0, stream>>>(
        mzi1, mzi2, mzi3, inph, outph1, outph2, outph3, P1, P2, P3);
    combine_kernel<<<128, 256, 0, stream>>>(P3, W, P34);
    stage1_kernel<<<B / 64, 512, 0, stream>>>(x, P1, alpha1, beta1, zbuf);
    stage2_kernel<<<B / 64, 512, 0, stream>>>(zbuf, P2, alpha2, beta2, zbuf);
    final_kernel<<<B / 64, 512, 0, stream>>>(zbuf, P34, bias, (float*)d_out);
}